// Round 10
// baseline (167.586 us; speedup 1.0000x reference)
//
#include <hip/hip_runtime.h>

// Problem constants (fixed by the reference):
//   B=8, N=256, IN_F=64, OUT_F=64, IN_E=32, OUT_E=64
#define BB    8
#define NN    256
#define OUTF  64
#define INE   32

using f4     = __attribute__((ext_vector_type(4))) float;
using f32x4  = __attribute__((ext_vector_type(4))) float;
using bf16x8 = __attribute__((ext_vector_type(8))) short;  // 8 bf16 = 4 VGPRs

// Device-global scratch; fully overwritten every call (deterministic).
__device__ float          g_node_x[BB * NN * OUTF];   // emb_node@W_node + b (pre-relu)
__device__ float          g_relu_sx[BB * NN * OUTF];  // relu(emb_node@W_nodes + b)
__device__ unsigned short g_wtb[OUTF * INE];          // W_edge^T as bf16, [f][k]

// f32 -> bf16 round-to-nearest-even (verified R2-R9, absmax pass).
static __device__ __forceinline__ unsigned short f2bf(float x) {
    unsigned u = __builtin_bit_cast(unsigned, x);
    u += 0x7fffu + ((u >> 16) & 1u);
    return (unsigned short)(u >> 16);
}

static __device__ __forceinline__ bf16x8 cvt8(f4 lo, f4 hi) {
    bf16x8 e;
    e[0] = (short)f2bf(lo.x); e[1] = (short)f2bf(lo.y);
    e[2] = (short)f2bf(lo.z); e[3] = (short)f2bf(lo.w);
    e[4] = (short)f2bf(hi.x); e[5] = (short)f2bf(hi.y);
    e[6] = (short)f2bf(hi.z); e[7] = (short)f2bf(hi.w);
    return e;
}

static __device__ __forceinline__ f4 relu4(f4 v) {
    f4 r;
    r.x = fmaxf(v.x, 0.f); r.y = fmaxf(v.y, 0.f);
    r.z = fmaxf(v.z, 0.f); r.w = fmaxf(v.w, 0.f);
    return r;
}

// ---------------------------------------------------------------------------
// Kernel 1: node projections (16 rows/block) + one-time W_edge^T bf16 prep.
// (unchanged from R8/R9)
// ---------------------------------------------------------------------------
__global__ __launch_bounds__(256) void node_proj(
    const float* __restrict__ emb_node,  // [B*N, 64]
    const float* __restrict__ W1, const float* __restrict__ b1,
    const float* __restrict__ W2, const float* __restrict__ b2,
    const float* __restrict__ W_edge)    // [32, 64]
{
    __shared__ float sW1[64][64];
    __shared__ float sW2[64][64];
    __shared__ float sE[16][64];

    const int tid = threadIdx.x;

    if (blockIdx.x == 0) {               // prep W_edge^T bf16 (2 KB), L2-hot later
        const int f  = tid >> 2;
        const int k0 = (tid & 3) * 8;
#pragma unroll
        for (int j = 0; j < 8; ++j)
            g_wtb[f * INE + k0 + j] = f2bf(W_edge[(k0 + j) * OUTF + f]);
    }

    const f4* w1v = (const f4*)W1;
    const f4* w2v = (const f4*)W2;
    f4* s1 = (f4*)&sW1[0][0];
    f4* s2 = (f4*)&sW2[0][0];
#pragma unroll
    for (int i = 0; i < 4; ++i) {
        s1[tid + i * 256] = w1v[tid + i * 256];
        s2[tid + i * 256] = w2v[tid + i * 256];
    }
    const int row0 = blockIdx.x * 16;
    ((f4*)&sE[0][0])[tid] = ((const f4*)(emb_node + row0 * 64))[tid];
    __syncthreads();

    const int s = tid >> 6;    // 0..3
    const int f = tid & 63;
    float a1[4], a2[4];
    const float bb1 = b1[f], bb2 = b2[f];
#pragma unroll
    for (int j = 0; j < 4; ++j) { a1[j] = bb1; a2[j] = bb2; }
#pragma unroll
    for (int k = 0; k < 64; ++k) {
        const float w1 = sW1[k][f];
        const float w2 = sW2[k][f];
#pragma unroll
        for (int j = 0; j < 4; ++j) {
            const float e = sE[s + 4 * j][k];
            a1[j] = fmaf(e, w1, a1[j]);
            a2[j] = fmaf(e, w2, a2[j]);
        }
    }
#pragma unroll
    for (int j = 0; j < 4; ++j) {
        const int row = row0 + s + 4 * j;
        g_node_x[row * 64 + f]  = a1[j];
        g_relu_sx[row * 64 + f] = fmaxf(a2[j], 0.f);
    }
}

// ---------------------------------------------------------------------------
// Kernel 2: R9's no-staging MFMA pipeline, restructured for VGPR <= 64
// (the m69 occupancy cliff; R8 profiled 68 VGPR -> 16-wave cap -> 27.8% occ).
// Register evictions, all to the idle LDS pipe:
//   wfrag[4] (16 VGPR) -> sWt  (bf16, 40-short row stride: ~2-way reads, free)
//   bias[4]  (16 VGPR) -> sBias (broadcast f4 reads; MFMA C-operand per use)
//   A row    ( 1 VGPR + 4 VMEM) -> sA (staged once, broadcast reads)
// ft-loop split into 2 halves (wf 8 + acc 8 live at a time), sched_barrier(0)
// after each half pins the window: peak ~58-62 regs. launch_bounds(256,8)
// caps at 64 -> 8 waves/SIMD possible. E loads keep the R9 depth-2 prefetch.
// ---------------------------------------------------------------------------
__global__ __launch_bounds__(256, 8) void edge_agg(
    const float* __restrict__ A,         // [B,N,N]
    const float* __restrict__ emb_edge,  // [B,N,N,32]
    const float* __restrict__ b_edge,    // [64]
    float* __restrict__ node_out,        // [B,N,64]
    float* __restrict__ edge_out)        // [B,N,N,64]
{
    __shared__ unsigned short sWt[64 * 40]; // 5120 B, W^T bf16, row stride 40
    __shared__ float sBias[64];             //  256 B
    __shared__ float sA[256];               // 1024 B
    __shared__ float sRed[4][64];           // 1024 B

    const int tid  = threadIdx.x;
    const int bn   = blockIdx.x;         // b*256 + n
    const int b    = bn >> 8;
    const int wave = tid >> 6;
    const int lane = tid & 63;
    const int c    = lane & 15;          // m within 16-tile / f-row of W^T
    const int q    = lane >> 4;          // k-quad & f-quad selector
    const int wbase = wave * 64;

    // ---- stage W^T (4 KB contiguous), bias, A row into LDS ----
    {
        const f4 wv = *(const f4*)((const unsigned short*)g_wtb + tid * 8);
        *(f4*)&sWt[(tid >> 2) * 40 + (tid & 3) * 8] = wv;
        if (tid < 16) ((f4*)sBias)[tid] = ((const f4*)b_edge)[tid];
        if (tid < 64) ((f4*)sA)[tid] = ((const f4*)(A + (size_t)bn * NN))[tid];
    }

    const float* ebase = emb_edge + (size_t)bn * (NN * INE);
    const float* nx    = g_node_x + b * (NN * OUTF);
    float*       eo    = edge_out + (size_t)bn * (NN * OUTF);

    // prologue: issue mt=0 E loads before the barrier (overlap staging)
    const float* rp0 = ebase + (wbase + c) * INE + q * 8;
    f4 plo = *(const f4*)rp0;            // cached: lo/hi share the line
    f4 phi = *(const f4*)(rp0 + 4);

    __syncthreads();

    f4 agg[4];
#pragma unroll
    for (int ft = 0; ft < 4; ++ft) { agg[ft].x = 0.f; agg[ft].y = 0.f; agg[ft].z = 0.f; agg[ft].w = 0.f; }

#pragma unroll
    for (int mt = 0; mt < 4; ++mt) {
        const int m = wbase + mt * 16 + c;

        const f4 lo = plo;
        const f4 hi = phi;
        // issue NEXT tile's loads before this tile's compute (depth-2)
        if (mt < 3) {
            const float* rpn = ebase + (m + 16) * INE + q * 8;
            plo = *(const f4*)rpn;
            phi = *(const f4*)(rpn + 4);
        }

        const bf16x8 ef = cvt8(lo, hi);
        const float  a  = sA[m];                       // LDS broadcast

#pragma unroll
        for (int h = 0; h < 2; ++h) {                  // ft pairs {0,1},{2,3}
            const int ftA = h * 2;
            const int ftB = ftA + 1;
            const bf16x8 wfA = *(const bf16x8*)&sWt[(ftA * 16 + c) * 40 + q * 8];
            const bf16x8 wfB = *(const bf16x8*)&sWt[(ftB * 16 + c) * 40 + q * 8];
            const f4     cbA = *(const f4*)&sBias[ftA * 16 + q * 4];
            const f4     cbB = *(const f4*)&sBias[ftB * 16 + q * 4];

            const f32x4 accA = __builtin_amdgcn_mfma_f32_16x16x32_bf16(wfA, ef, cbA, 0, 0, 0);
            const f32x4 accB = __builtin_amdgcn_mfma_f32_16x16x32_bf16(wfB, ef, cbB, 0, 0, 0);

            // fused epilogue: lane holds 4 consecutive f for row m
            {
                const int fb  = ftA * 16 + q * 4;
                const f4  nxv = *(const f4*)&nx[m * OUTF + fb];  // L2-hot
                *(f4*)&eo[(size_t)m * OUTF + fb] = relu4(accA);  // plain store
                agg[ftA].x = fmaf(a * accA.x, nxv.x, agg[ftA].x);
                agg[ftA].y = fmaf(a * accA.y, nxv.y, agg[ftA].y);
                agg[ftA].z = fmaf(a * accA.z, nxv.z, agg[ftA].z);
                agg[ftA].w = fmaf(a * accA.w, nxv.w, agg[ftA].w);
            }
            {
                const int fb  = ftB * 16 + q * 4;
                const f4  nxv = *(const f4*)&nx[m * OUTF + fb];
                *(f4*)&eo[(size_t)m * OUTF + fb] = relu4(accB);
                agg[ftB].x = fmaf(a * accB.x, nxv.x, agg[ftB].x);
                agg[ftB].y = fmaf(a * accB.y, nxv.y, agg[ftB].y);
                agg[ftB].z = fmaf(a * accB.z, nxv.z, agg[ftB].z);
                agg[ftB].w = fmaf(a * accB.w, nxv.w, agg[ftB].w);
            }
            // pin the half-window: no cross-half/iteration reg duplication
            __builtin_amdgcn_sched_barrier(0);
        }
    }

    // ---- reduce over the 16 m-columns (lane bits 0..3 == c) ----
#pragma unroll
    for (int ft = 0; ft < 4; ++ft) {
#pragma unroll
        for (int s = 1; s < 16; s <<= 1) {
            agg[ft].x += __shfl_xor(agg[ft].x, s);
            agg[ft].y += __shfl_xor(agg[ft].y, s);
            agg[ft].z += __shfl_xor(agg[ft].z, s);
            agg[ft].w += __shfl_xor(agg[ft].w, s);
        }
    }
    if (c == 0) {
#pragma unroll
        for (int ft = 0; ft < 4; ++ft)
            *(f4*)&sRed[wave][ft * 16 + q * 4] = agg[ft];
    }
    __syncthreads();

    // ---- reduce across 4 waves, add relu(node_sx), store node_out ----
    if (tid < 64) {
        float s = sRed[0][tid] + sRed[1][tid] + sRed[2][tid] + sRed[3][tid];
        node_out[bn * OUTF + tid] = fmaxf(s, 0.f) + g_relu_sx[bn * OUTF + tid];
    }
}

// ---------------------------------------------------------------------------
extern "C" void kernel_launch(void* const* d_in, const int* in_sizes, int n_in,
                              void* d_out, int out_size, void* d_ws, size_t ws_size,
                              hipStream_t stream) {
    const float* A        = (const float*)d_in[0];
    const float* emb_node = (const float*)d_in[1];
    const float* emb_edge = (const float*)d_in[2];
    const float* W_node   = (const float*)d_in[3];
    const float* b_node   = (const float*)d_in[4];
    const float* W_nodes  = (const float*)d_in[5];
    const float* b_nodes  = (const float*)d_in[6];
    const float* W_edge   = (const float*)d_in[7];
    const float* b_edge   = (const float*)d_in[8];

    float* node_out = (float*)d_out;                 // [8,256,64]
    float* edge_out = node_out + BB * NN * OUTF;     // [8,256,256,64]

    node_proj<<<(BB * NN) / 16, 256, 0, stream>>>(emb_node, W_node, b_node,
                                                  W_nodes, b_nodes, W_edge);
    edge_agg<<<BB * NN, 256, 0, stream>>>(A, emb_edge, b_edge, node_out, edge_out);
}

// Round 11
// 54.974 us; speedup vs baseline: 3.0484x; 3.0484x over previous
//
#include <hip/hip_runtime.h>

// Problem constants (fixed by the reference):
//   B=8, N=256, IN_F=64, OUT_F=64, IN_E=32, OUT_E=64
#define BB    8
#define NN    256
#define OUTF  64
#define INE   32

using f4     = __attribute__((ext_vector_type(4))) float;
using f32x4  = __attribute__((ext_vector_type(4))) float;
using bf16x8 = __attribute__((ext_vector_type(8))) short;  // 8 bf16 = 4 VGPRs

// Device-global scratch; fully overwritten every call (deterministic).
__device__ float          g_node_x[BB * NN * OUTF];   // emb_node@W_node + b (pre-relu)
__device__ float          g_relu_sx[BB * NN * OUTF];  // relu(emb_node@W_nodes + b)
__device__ unsigned short g_wtb[OUTF * INE];          // W_edge^T as bf16, [f][k]

// f32 -> bf16 round-to-nearest-even (verified R2-R10, absmax pass).
static __device__ __forceinline__ unsigned short f2bf(float x) {
    unsigned u = __builtin_bit_cast(unsigned, x);
    u += 0x7fffu + ((u >> 16) & 1u);
    return (unsigned short)(u >> 16);
}

static __device__ __forceinline__ bf16x8 cvt8(f4 lo, f4 hi) {
    bf16x8 e;
    e[0] = (short)f2bf(lo.x); e[1] = (short)f2bf(lo.y);
    e[2] = (short)f2bf(lo.z); e[3] = (short)f2bf(lo.w);
    e[4] = (short)f2bf(hi.x); e[5] = (short)f2bf(hi.y);
    e[6] = (short)f2bf(hi.z); e[7] = (short)f2bf(hi.w);
    return e;
}

static __device__ __forceinline__ f4 relu4(f4 v) {
    f4 r;
    r.x = fmaxf(v.x, 0.f); r.y = fmaxf(v.y, 0.f);
    r.z = fmaxf(v.z, 0.f); r.w = fmaxf(v.w, 0.f);
    return r;
}

// ---------------------------------------------------------------------------
// Kernel 1: node projections (16 rows/block) + one-time W_edge^T bf16 prep.
// (unchanged from R8/R9 — isolate the edge_agg variable)
// ---------------------------------------------------------------------------
__global__ __launch_bounds__(256) void node_proj(
    const float* __restrict__ emb_node,  // [B*N, 64]
    const float* __restrict__ W1, const float* __restrict__ b1,
    const float* __restrict__ W2, const float* __restrict__ b2,
    const float* __restrict__ W_edge)    // [32, 64]
{
    __shared__ float sW1[64][64];
    __shared__ float sW2[64][64];
    __shared__ float sE[16][64];

    const int tid = threadIdx.x;

    if (blockIdx.x == 0) {               // prep W_edge^T bf16 (2 KB), L2-hot later
        const int f  = tid >> 2;
        const int k0 = (tid & 3) * 8;
#pragma unroll
        for (int j = 0; j < 8; ++j)
            g_wtb[f * INE + k0 + j] = f2bf(W_edge[(k0 + j) * OUTF + f]);
    }

    const f4* w1v = (const f4*)W1;
    const f4* w2v = (const f4*)W2;
    f4* s1 = (f4*)&sW1[0][0];
    f4* s2 = (f4*)&sW2[0][0];
#pragma unroll
    for (int i = 0; i < 4; ++i) {
        s1[tid + i * 256] = w1v[tid + i * 256];
        s2[tid + i * 256] = w2v[tid + i * 256];
    }
    const int row0 = blockIdx.x * 16;
    ((f4*)&sE[0][0])[tid] = ((const f4*)(emb_node + row0 * 64))[tid];
    __syncthreads();

    const int s = tid >> 6;    // 0..3
    const int f = tid & 63;
    float a1[4], a2[4];
    const float bb1 = b1[f], bb2 = b2[f];
#pragma unroll
    for (int j = 0; j < 4; ++j) { a1[j] = bb1; a2[j] = bb2; }
#pragma unroll
    for (int k = 0; k < 64; ++k) {
        const float w1 = sW1[k][f];
        const float w2 = sW2[k][f];
#pragma unroll
        for (int j = 0; j < 4; ++j) {
            const float e = sE[s + 4 * j][k];
            a1[j] = fmaf(e, w1, a1[j]);
            a2[j] = fmaf(e, w2, a2[j]);
        }
    }
#pragma unroll
    for (int j = 0; j < 4; ++j) {
        const int row = row0 + s + 4 * j;
        g_node_x[row * 64 + f]  = a1[j];
        g_relu_sx[row * 64 + f] = fmaxf(a2[j], 0.f);
    }
}

// ---------------------------------------------------------------------------
// Kernel 2: LOOP-FREE MFMA slab kernel. 2048 blocks x 1024 threads (16 waves).
// Wave w owns rows [16w, 16w+16) of its (b,n) tile — the mt loop of R9 is
// flattened into waves, so there is NO loop-carried register state:
//   wfrag/bias die at MFMA issue; acc dies in its epilogue; agg is computed
//   once and immediately shfl-reduced. Honest peak ~60 VGPR, no forcing
//   (R5/R7/R10 lesson: launch_bounds min-waves + MFMA state = spill disaster).
// Per wave: E row 32B cached loads -> bf16 frag -> 4x mfma_f32_16x16x32_bf16
// (R4-verified swapped maps: A=W^T[f][k], B=E[m][k], D[f][m]: f=ft*16+q*4+reg,
// m=c) -> relu f4 store + agg=a*acc*nx -> shfl_xor(c-bits) reduce ->
// sRed[wave] -> single barrier -> 64-thread final reduce.
// Latency hiding comes from wave COUNT (16-32/CU, ~7 loads in flight each),
// not from a per-wave pipeline.
// ---------------------------------------------------------------------------
__global__ __launch_bounds__(1024) void edge_agg(
    const float* __restrict__ A,         // [B,N,N]
    const float* __restrict__ emb_edge,  // [B,N,N,32]
    const float* __restrict__ b_edge,    // [64]
    float* __restrict__ node_out,        // [B,N,64]
    float* __restrict__ edge_out)        // [B,N,N,64]
{
    __shared__ float sRed[16][64];       // 4 KB — only LDS in the kernel

    const int tid  = threadIdx.x;
    const int bn   = blockIdx.x;         // b*256 + n
    const int b    = bn >> 8;
    const int wave = tid >> 6;           // 0..15
    const int lane = tid & 63;
    const int c    = lane & 15;          // m within slab / f-row of W^T
    const int q    = lane >> 4;          // k-quad & f-quad selector
    const int m    = wave * 16 + c;      // this lane's row

    // ---- independent loads first: E row (32B cached), A, W^T frags, bias ----
    const float* rp = emb_edge + (size_t)bn * (NN * INE) + m * INE + q * 8;
    const f4 lo = *(const f4*)rp;        // lo/hi share a cache line
    const f4 hi = *(const f4*)(rp + 4);
    const float a = A[(size_t)bn * NN + m];   // 4 lanes/addr merge

    bf16x8 wfrag[4];
    f4     bias[4];
#pragma unroll
    for (int ft = 0; ft < 4; ++ft) {
        wfrag[ft] = *(const bf16x8*)&g_wtb[(ft * 16 + c) * INE + q * 8];  // L2-hot
        bias[ft]  = *(const f4*)&b_edge[ft * 16 + q * 4];
    }

    const bf16x8 ef = cvt8(lo, hi);

    // ---- 4 MFMAs (wfrag/bias die here; acc born) ----
    f32x4 acc[4];
#pragma unroll
    for (int ft = 0; ft < 4; ++ft)
        acc[ft] = __builtin_amdgcn_mfma_f32_16x16x32_bf16(
            wfrag[ft], ef, bias[ft], 0, 0, 0);

    // ---- fused epilogue per ft: relu f4 store + agg, acc dies progressively --
    const float* nx = g_node_x + b * (NN * OUTF);
    float*       eo = edge_out + (size_t)bn * (NN * OUTF);
    f4 agg[4];
#pragma unroll
    for (int ft = 0; ft < 4; ++ft) {
        const int fb  = ft * 16 + q * 4;
        const f4  v   = acc[ft];                         // pre-relu edge_x
        const f4  nxv = *(const f4*)&nx[m * OUTF + fb];  // L2-hot
        *(f4*)&eo[(size_t)m * OUTF + fb] = relu4(v);     // plain store, L2 merges
        agg[ft].x = a * v.x * nxv.x;
        agg[ft].y = a * v.y * nxv.y;
        agg[ft].z = a * v.z * nxv.z;
        agg[ft].w = a * v.w * nxv.w;
    }

    // ---- reduce over the 16 m-columns of this slab (lane bits 0..3 == c) ----
#pragma unroll
    for (int ft = 0; ft < 4; ++ft) {
#pragma unroll
        for (int s = 1; s < 16; s <<= 1) {
            agg[ft].x += __shfl_xor(agg[ft].x, s);
            agg[ft].y += __shfl_xor(agg[ft].y, s);
            agg[ft].z += __shfl_xor(agg[ft].z, s);
            agg[ft].w += __shfl_xor(agg[ft].w, s);
        }
    }
    if (c == 0) {
#pragma unroll
        for (int ft = 0; ft < 4; ++ft)
            *(f4*)&sRed[wave][ft * 16 + q * 4] = agg[ft];
    }
    __syncthreads();

    // ---- final reduce across 16 waves, add relu(node_sx), store node_out ----
    if (tid < 64) {
        float s = 0.f;
#pragma unroll
        for (int w = 0; w < 16; ++w) s += sRed[w][tid];
        node_out[bn * OUTF + tid] = fmaxf(s, 0.f) + g_relu_sx[bn * OUTF + tid];
    }
}

// ---------------------------------------------------------------------------
extern "C" void kernel_launch(void* const* d_in, const int* in_sizes, int n_in,
                              void* d_out, int out_size, void* d_ws, size_t ws_size,
                              hipStream_t stream) {
    const float* A        = (const float*)d_in[0];
    const float* emb_node = (const float*)d_in[1];
    const float* emb_edge = (const float*)d_in[2];
    const float* W_node   = (const float*)d_in[3];
    const float* b_node   = (const float*)d_in[4];
    const float* W_nodes  = (const float*)d_in[5];
    const float* b_nodes  = (const float*)d_in[6];
    const float* W_edge   = (const float*)d_in[7];
    const float* b_edge   = (const float*)d_in[8];

    float* node_out = (float*)d_out;                 // [8,256,64]
    float* edge_out = node_out + BB * NN * OUTF;     // [8,256,256,64]

    node_proj<<<(BB * NN) / 16, 256, 0, stream>>>(emb_node, W_node, b_node,
                                                  W_nodes, b_nodes, W_edge);
    edge_agg<<<BB * NN, 1024, 0, stream>>>(A, emb_edge, b_edge, node_out, edge_out);
}

// Round 12
// 49.431 us; speedup vs baseline: 3.3903x; 1.1121x over previous
//
#include <hip/hip_runtime.h>

// Problem constants (fixed by the reference):
//   B=8, N=256, IN_F=64, OUT_F=64, IN_E=32, OUT_E=64
#define BB    8
#define NN    256
#define OUTF  64
#define INE   32

using f4     = __attribute__((ext_vector_type(4))) float;
using f32x4  = __attribute__((ext_vector_type(4))) float;
using bf16x8 = __attribute__((ext_vector_type(8))) short;  // 8 bf16 = 4 VGPRs

// Device-global scratch; fully overwritten every call (deterministic).
__device__ float          g_node_x[BB * NN * OUTF];   // emb_node@W_node + b (pre-relu)
__device__ float          g_relu_sx[BB * NN * OUTF];  // relu(emb_node@W_nodes + b)
__device__ unsigned short g_wtb[OUTF * INE];          // W_edge^T as bf16, [f][k]

// f32 -> bf16 round-to-nearest-even (verified R2-R11, absmax pass).
static __device__ __forceinline__ unsigned short f2bf(float x) {
    unsigned u = __builtin_bit_cast(unsigned, x);
    u += 0x7fffu + ((u >> 16) & 1u);
    return (unsigned short)(u >> 16);
}

static __device__ __forceinline__ bf16x8 cvt8(f4 lo, f4 hi) {
    bf16x8 e;
    e[0] = (short)f2bf(lo.x); e[1] = (short)f2bf(lo.y);
    e[2] = (short)f2bf(lo.z); e[3] = (short)f2bf(lo.w);
    e[4] = (short)f2bf(hi.x); e[5] = (short)f2bf(hi.y);
    e[6] = (short)f2bf(hi.z); e[7] = (short)f2bf(hi.w);
    return e;
}

static __device__ __forceinline__ f4 relu4(f4 v) {
    f4 r;
    r.x = fmaxf(v.x, 0.f); r.y = fmaxf(v.y, 0.f);
    r.z = fmaxf(v.z, 0.f); r.w = fmaxf(v.w, 0.f);
    return r;
}

// ---------------------------------------------------------------------------
// Kernel 1: node projections (16 rows/block) + one-time W_edge^T bf16 prep.
// (unchanged since R8 — isolate the edge_agg variable)
// ---------------------------------------------------------------------------
__global__ __launch_bounds__(256) void node_proj(
    const float* __restrict__ emb_node,  // [B*N, 64]
    const float* __restrict__ W1, const float* __restrict__ b1,
    const float* __restrict__ W2, const float* __restrict__ b2,
    const float* __restrict__ W_edge)    // [32, 64]
{
    __shared__ float sW1[64][64];
    __shared__ float sW2[64][64];
    __shared__ float sE[16][64];

    const int tid = threadIdx.x;

    if (blockIdx.x == 0) {               // prep W_edge^T bf16 (2 KB), L2-hot later
        const int f  = tid >> 2;
        const int k0 = (tid & 3) * 8;
#pragma unroll
        for (int j = 0; j < 8; ++j)
            g_wtb[f * INE + k0 + j] = f2bf(W_edge[(k0 + j) * OUTF + f]);
    }

    const f4* w1v = (const f4*)W1;
    const f4* w2v = (const f4*)W2;
    f4* s1 = (f4*)&sW1[0][0];
    f4* s2 = (f4*)&sW2[0][0];
#pragma unroll
    for (int i = 0; i < 4; ++i) {
        s1[tid + i * 256] = w1v[tid + i * 256];
        s2[tid + i * 256] = w2v[tid + i * 256];
    }
    const int row0 = blockIdx.x * 16;
    ((f4*)&sE[0][0])[tid] = ((const f4*)(emb_node + row0 * 64))[tid];
    __syncthreads();

    const int s = tid >> 6;    // 0..3
    const int f = tid & 63;
    float a1[4], a2[4];
    const float bb1 = b1[f], bb2 = b2[f];
#pragma unroll
    for (int j = 0; j < 4; ++j) { a1[j] = bb1; a2[j] = bb2; }
#pragma unroll
    for (int k = 0; k < 64; ++k) {
        const float w1 = sW1[k][f];
        const float w2 = sW2[k][f];
#pragma unroll
        for (int j = 0; j < 4; ++j) {
            const float e = sE[s + 4 * j][k];
            a1[j] = fmaf(e, w1, a1[j]);
            a2[j] = fmaf(e, w2, a2[j]);
        }
    }
#pragma unroll
    for (int j = 0; j < 4; ++j) {
        const int row = row0 + s + 4 * j;
        g_node_x[row * 64 + f]  = a1[j];
        g_relu_sx[row * 64 + f] = fmaxf(a2[j], 0.f);
    }
}

// ---------------------------------------------------------------------------
// Kernel 2: R10's LDS-evicted MFMA pipeline WITHOUT the launch_bounds forcing
// (the single variable vs R10; vs R9 the variable is register placement).
// R10 proved this body correct; its 167 us came from the forced (256,8) bound
// spilling the working set (VGPR=32 + 195 MB scratch). Unforced, the honest
// live set is ~40-56 VGPR: wfrag -> sWt (bf16, stride-40 rows: <=2-way reads,
// free per m136), bias -> sBias (broadcast), A -> sA (broadcast). 256-thread
// blocks keep R9's fine scheduling granularity (R11's 1024-thread blocks
// showed 65% occupancy but coarse-quantum wall regression).
// ---------------------------------------------------------------------------
__global__ __launch_bounds__(256) void edge_agg(
    const float* __restrict__ A,         // [B,N,N]
    const float* __restrict__ emb_edge,  // [B,N,N,32]
    const float* __restrict__ b_edge,    // [64]
    float* __restrict__ node_out,        // [B,N,64]
    float* __restrict__ edge_out)        // [B,N,N,64]
{
    __shared__ unsigned short sWt[64 * 40]; // 5120 B, W^T bf16, row stride 40
    __shared__ float sBias[64];             //  256 B
    __shared__ float sA[256];               // 1024 B
    __shared__ float sRed[4][64];           // 1024 B

    const int tid  = threadIdx.x;
    const int bn   = blockIdx.x;         // b*256 + n
    const int b    = bn >> 8;
    const int wave = tid >> 6;
    const int lane = tid & 63;
    const int c    = lane & 15;          // m within 16-tile / f-row of W^T
    const int q    = lane >> 4;          // k-quad & f-quad selector
    const int wbase = wave * 64;

    // ---- stage W^T (4 KB contiguous), bias, A row into LDS ----
    {
        const f4 wv = *(const f4*)((const unsigned short*)g_wtb + tid * 8);
        *(f4*)&sWt[(tid >> 2) * 40 + (tid & 3) * 8] = wv;
        if (tid < 16) ((f4*)sBias)[tid] = ((const f4*)b_edge)[tid];
        if (tid < 64) ((f4*)sA)[tid] = ((const f4*)(A + (size_t)bn * NN))[tid];
    }

    const float* ebase = emb_edge + (size_t)bn * (NN * INE);
    const float* nx    = g_node_x + b * (NN * OUTF);
    float*       eo    = edge_out + (size_t)bn * (NN * OUTF);

    // prologue: issue mt=0 E loads before the barrier (overlap staging)
    const float* rp0 = ebase + (wbase + c) * INE + q * 8;
    f4 plo = *(const f4*)rp0;            // cached: lo/hi share the line
    f4 phi = *(const f4*)(rp0 + 4);

    __syncthreads();

    f4 agg[4];
#pragma unroll
    for (int ft = 0; ft < 4; ++ft) { agg[ft].x = 0.f; agg[ft].y = 0.f; agg[ft].z = 0.f; agg[ft].w = 0.f; }

#pragma unroll
    for (int mt = 0; mt < 4; ++mt) {
        const int m = wbase + mt * 16 + c;

        const f4 lo = plo;
        const f4 hi = phi;
        // issue NEXT tile's loads before this tile's compute (depth-2)
        if (mt < 3) {
            const float* rpn = ebase + (m + 16) * INE + q * 8;
            plo = *(const f4*)rpn;
            phi = *(const f4*)(rpn + 4);
        }

        const bf16x8 ef = cvt8(lo, hi);
        const float  a  = sA[m];                       // LDS broadcast

#pragma unroll
        for (int h = 0; h < 2; ++h) {                  // ft pairs {0,1},{2,3}
            const int ftA = h * 2;
            const int ftB = ftA + 1;
            const bf16x8 wfA = *(const bf16x8*)&sWt[(ftA * 16 + c) * 40 + q * 8];
            const bf16x8 wfB = *(const bf16x8*)&sWt[(ftB * 16 + c) * 40 + q * 8];
            const f4     cbA = *(const f4*)&sBias[ftA * 16 + q * 4];
            const f4     cbB = *(const f4*)&sBias[ftB * 16 + q * 4];

            const f32x4 accA = __builtin_amdgcn_mfma_f32_16x16x32_bf16(wfA, ef, cbA, 0, 0, 0);
            const f32x4 accB = __builtin_amdgcn_mfma_f32_16x16x32_bf16(wfB, ef, cbB, 0, 0, 0);

            // fused epilogue: lane holds 4 consecutive f for row m
            {
                const int fb  = ftA * 16 + q * 4;
                const f4  nxv = *(const f4*)&nx[m * OUTF + fb];  // L2-hot
                *(f4*)&eo[(size_t)m * OUTF + fb] = relu4(accA);  // plain store
                agg[ftA].x = fmaf(a * accA.x, nxv.x, agg[ftA].x);
                agg[ftA].y = fmaf(a * accA.y, nxv.y, agg[ftA].y);
                agg[ftA].z = fmaf(a * accA.z, nxv.z, agg[ftA].z);
                agg[ftA].w = fmaf(a * accA.w, nxv.w, agg[ftA].w);
            }
            {
                const int fb  = ftB * 16 + q * 4;
                const f4  nxv = *(const f4*)&nx[m * OUTF + fb];
                *(f4*)&eo[(size_t)m * OUTF + fb] = relu4(accB);
                agg[ftB].x = fmaf(a * accB.x, nxv.x, agg[ftB].x);
                agg[ftB].y = fmaf(a * accB.y, nxv.y, agg[ftB].y);
                agg[ftB].z = fmaf(a * accB.z, nxv.z, agg[ftB].z);
                agg[ftB].w = fmaf(a * accB.w, nxv.w, agg[ftB].w);
            }
            // pin the half-window: no cross-half/iteration reg duplication
            __builtin_amdgcn_sched_barrier(0);
        }
    }

    // ---- reduce over the 16 m-columns (lane bits 0..3 == c) ----
#pragma unroll
    for (int ft = 0; ft < 4; ++ft) {
#pragma unroll
        for (int s = 1; s < 16; s <<= 1) {
            agg[ft].x += __shfl_xor(agg[ft].x, s);
            agg[ft].y += __shfl_xor(agg[ft].y, s);
            agg[ft].z += __shfl_xor(agg[ft].z, s);
            agg[ft].w += __shfl_xor(agg[ft].w, s);
        }
    }
    if (c == 0) {
#pragma unroll
        for (int ft = 0; ft < 4; ++ft)
            *(f4*)&sRed[wave][ft * 16 + q * 4] = agg[ft];
    }
    __syncthreads();

    // ---- reduce across 4 waves, add relu(node_sx), store node_out ----
    if (tid < 64) {
        float s = sRed[0][tid] + sRed[1][tid] + sRed[2][tid] + sRed[3][tid];
        node_out[bn * OUTF + tid] = fmaxf(s, 0.f) + g_relu_sx[bn * OUTF + tid];
    }
}

// ---------------------------------------------------------------------------
extern "C" void kernel_launch(void* const* d_in, const int* in_sizes, int n_in,
                              void* d_out, int out_size, void* d_ws, size_t ws_size,
                              hipStream_t stream) {
    const float* A        = (const float*)d_in[0];
    const float* emb_node = (const float*)d_in[1];
    const float* emb_edge = (const float*)d_in[2];
    const float* W_node   = (const float*)d_in[3];
    const float* b_node   = (const float*)d_in[4];
    const float* W_nodes  = (const float*)d_in[5];
    const float* b_nodes  = (const float*)d_in[6];
    const float* W_edge   = (const float*)d_in[7];
    const float* b_edge   = (const float*)d_in[8];

    float* node_out = (float*)d_out;                 // [8,256,64]
    float* edge_out = node_out + BB * NN * OUTF;     // [8,256,256,64]

    node_proj<<<(BB * NN) / 16, 256, 0, stream>>>(emb_node, W_node, b_node,
                                                  W_nodes, b_nodes, W_edge);
    edge_agg<<<BB * NN, 256, 0, stream>>>(A, emb_edge, b_edge, node_out, edge_out);
}

// Round 18
// 48.088 us; speedup vs baseline: 3.4850x; 1.0279x over previous
//
#include <hip/hip_runtime.h>

// Problem constants (fixed by the reference):
//   B=8, N=256, IN_F=64, OUT_F=64, IN_E=32, OUT_E=64
#define BB    8
#define NN    256
#define OUTF  64
#define INE   32

using f4     = __attribute__((ext_vector_type(4))) float;
using f32x4  = __attribute__((ext_vector_type(4))) float;
using bf16x8 = __attribute__((ext_vector_type(8))) short;  // 8 bf16 = 4 VGPRs

// Device-global scratch; fully overwritten every call (deterministic).
__device__ float          g_node_x[BB * NN * OUTF];   // emb_node@W_node + b (pre-relu)
__device__ float          g_relu_sx[BB * NN * OUTF];  // relu(emb_node@W_nodes + b)
__device__ unsigned short g_wtb[OUTF * INE];          // W_edge^T as bf16, [f][k]

// f32 -> bf16 round-to-nearest-even (verified R2-R12, absmax pass).
static __device__ __forceinline__ unsigned short f2bf(float x) {
    unsigned u = __builtin_bit_cast(unsigned, x);
    u += 0x7fffu + ((u >> 16) & 1u);
    return (unsigned short)(u >> 16);
}

static __device__ __forceinline__ bf16x8 cvt8(f4 lo, f4 hi) {
    bf16x8 e;
    e[0] = (short)f2bf(lo.x); e[1] = (short)f2bf(lo.y);
    e[2] = (short)f2bf(lo.z); e[3] = (short)f2bf(lo.w);
    e[4] = (short)f2bf(hi.x); e[5] = (short)f2bf(hi.y);
    e[6] = (short)f2bf(hi.z); e[7] = (short)f2bf(hi.w);
    return e;
}

static __device__ __forceinline__ f4 relu4(f4 v) {
    f4 r;
    r.x = fmaxf(v.x, 0.f); r.y = fmaxf(v.y, 0.f);
    r.z = fmaxf(v.z, 0.f); r.w = fmaxf(v.w, 0.f);
    return r;
}

// ---------------------------------------------------------------------------
// Kernel 1: node projections (16 rows/block) + one-time W_edge^T bf16 prep.
// ---------------------------------------------------------------------------
__global__ __launch_bounds__(256) void node_proj(
    const float* __restrict__ emb_node,  // [B*N, 64]
    const float* __restrict__ W1, const float* __restrict__ b1,
    const float* __restrict__ W2, const float* __restrict__ b2,
    const float* __restrict__ W_edge)    // [32, 64]
{
    __shared__ float sW1[64][64];
    __shared__ float sW2[64][64];
    __shared__ float sE[16][64];

    const int tid = threadIdx.x;

    if (blockIdx.x == 0) {               // prep W_edge^T bf16 (2 KB), L2-hot later
        const int f  = tid >> 2;
        const int k0 = (tid & 3) * 8;
#pragma unroll
        for (int j = 0; j < 8; ++j)
            g_wtb[f * INE + k0 + j] = f2bf(W_edge[(k0 + j) * OUTF + f]);
    }

    const f4* w1v = (const f4*)W1;
    const f4* w2v = (const f4*)W2;
    f4* s1 = (f4*)&sW1[0][0];
    f4* s2 = (f4*)&sW2[0][0];
#pragma unroll
    for (int i = 0; i < 4; ++i) {
        s1[tid + i * 256] = w1v[tid + i * 256];
        s2[tid + i * 256] = w2v[tid + i * 256];
    }
    const int row0 = blockIdx.x * 16;
    ((f4*)&sE[0][0])[tid] = ((const f4*)(emb_node + row0 * 64))[tid];
    __syncthreads();

    const int s = tid >> 6;    // 0..3
    const int f = tid & 63;
    float a1[4], a2[4];
    const float bb1 = b1[f], bb2 = b2[f];
#pragma unroll
    for (int j = 0; j < 4; ++j) { a1[j] = bb1; a2[j] = bb2; }
#pragma unroll
    for (int k = 0; k < 64; ++k) {
        const float w1 = sW1[k][f];
        const float w2 = sW2[k][f];
#pragma unroll
        for (int j = 0; j < 4; ++j) {
            const float e = sE[s + 4 * j][k];
            a1[j] = fmaf(e, w1, a1[j]);
            a2[j] = fmaf(e, w2, a2[j]);
        }
    }
#pragma unroll
    for (int j = 0; j < 4; ++j) {
        const int row = row0 + s + 4 * j;
        g_node_x[row * 64 + f]  = a1[j];
        g_relu_sx[row * 64 + f] = fmaxf(a2[j], 0.f);
    }
}

// ---------------------------------------------------------------------------
// Kernel 2 (R9 champion): NO-STAGING MFMA with BOUNDED 2-deep pipeline.
// 2048 blocks x 256 threads (4 waves), LDS = 1 KB. Wave w owns rows
// [64w, 64w+64); per mt (16 rows): cached 32B E-row loads -> bf16 frag ->
// 4x mfma_f32_16x16x32_bf16 (swapped-operand maps: A=W^T, B=E, D[f][m]) ->
// fused epilogue (relu f4 plain store — sector-perfect — + agg fma against
// L2-hot node_x). Depth-2 manual prefetch + sched_barrier(0) per mt pins
// one acc set live. No min-waves clause (R5/R7/R10: forcing => spills).
// Measured (R9): 48.1 us wall; bytes at floor; mixed-stream rate ceiling.
// ---------------------------------------------------------------------------
__global__ __launch_bounds__(256) void edge_agg(
    const float* __restrict__ A,         // [B,N,N]
    const float* __restrict__ emb_edge,  // [B,N,N,32]
    const float* __restrict__ b_edge,    // [64]
    float* __restrict__ node_out,        // [B,N,64]
    float* __restrict__ edge_out)        // [B,N,N,64]
{
    __shared__ float sRed[4][64];        // only LDS in the kernel

    const int tid  = threadIdx.x;
    const int bn   = blockIdx.x;         // b*256 + n
    const int b    = bn >> 8;
    const int wave = tid >> 6;
    const int lane = tid & 63;
    const int c    = lane & 15;          // m within 16-tile / f-row of W^T
    const int q    = lane >> 4;          // k-quad & f-quad selector
    const int wbase = wave * 64;

    // ---- L2-hot constants: W^T fragments + bias ----
    bf16x8 wfrag[4];
    f4     bias[4];
#pragma unroll
    for (int ft = 0; ft < 4; ++ft) {
        wfrag[ft] = *(const bf16x8*)&g_wtb[(ft * 16 + c) * INE + q * 8];
        bias[ft]  = *(const f4*)&b_edge[ft * 16 + q * 4];
    }

    const float* ebase = emb_edge + (size_t)bn * (NN * INE);
    const float* Arow  = A + (size_t)bn * NN;
    const float* nx    = g_node_x + b * (NN * OUTF);
    float*       eo    = edge_out + (size_t)bn * (NN * OUTF);

    f4 agg[4];
#pragma unroll
    for (int ft = 0; ft < 4; ++ft) { agg[ft].x = 0.f; agg[ft].y = 0.f; agg[ft].z = 0.f; agg[ft].w = 0.f; }

    // ---- prologue: issue mt=0 loads ----
    const float* rp0 = ebase + (wbase + c) * INE + q * 8;
    f4    plo = *(const f4*)rp0;         // cached: lo/hi share the line
    f4    phi = *(const f4*)(rp0 + 4);
    float pa  = Arow[wbase + c];

#pragma unroll
    for (int mt = 0; mt < 4; ++mt) {
        const int m = wbase + mt * 16 + c;

        // current tile operands
        const f4    lo = plo;
        const f4    hi = phi;
        const float a  = pa;

        // ---- issue NEXT tile's loads before this tile's compute ----
        if (mt < 3) {
            const float* rpn = ebase + (m + 16) * INE + q * 8;
            plo = *(const f4*)rpn;
            phi = *(const f4*)(rpn + 4);
            pa  = Arow[m + 16];
        }

        const bf16x8 ef = cvt8(lo, hi);

        f32x4 acc[4];
#pragma unroll
        for (int ft = 0; ft < 4; ++ft)
            acc[ft] = __builtin_amdgcn_mfma_f32_16x16x32_bf16(
                wfrag[ft], ef, bias[ft], 0, 0, 0);

        // fused epilogue: lane holds 4 consecutive f for row m
#pragma unroll
        for (int ft = 0; ft < 4; ++ft) {
            const int fb  = ft * 16 + q * 4;
            const f4  v   = acc[ft];                         // pre-relu edge_x
            const f4  nxv = *(const f4*)&nx[m * OUTF + fb];  // L2-hot
            *(f4*)&eo[(size_t)m * OUTF + fb] = relu4(v);     // plain store: L2 merges
            agg[ft].x = fmaf(a * v.x, nxv.x, agg[ft].x);
            agg[ft].y = fmaf(a * v.y, nxv.y, agg[ft].y);
            agg[ft].z = fmaf(a * v.z, nxv.z, agg[ft].z);
            agg[ft].w = fmaf(a * v.w, nxv.w, agg[ft].w);
        }

        // pin the 2-deep pipeline: no cross-mt MFMA/acc duplication
        __builtin_amdgcn_sched_barrier(0);
    }

    // ---- reduce over the 16 m-columns (lane bits 0..3 == c) ----
#pragma unroll
    for (int ft = 0; ft < 4; ++ft) {
#pragma unroll
        for (int s = 1; s < 16; s <<= 1) {
            agg[ft].x += __shfl_xor(agg[ft].x, s);
            agg[ft].y += __shfl_xor(agg[ft].y, s);
            agg[ft].z += __shfl_xor(agg[ft].z, s);
            agg[ft].w += __shfl_xor(agg[ft].w, s);
        }
    }
    if (c == 0) {
#pragma unroll
        for (int ft = 0; ft < 4; ++ft)
            *(f4*)&sRed[wave][ft * 16 + q * 4] = agg[ft];
    }
    __syncthreads();

    // ---- reduce across 4 waves, add relu(node_sx), store node_out ----
    if (tid < 64) {
        float s = sRed[0][tid] + sRed[1][tid] + sRed[2][tid] + sRed[3][tid];
        node_out[bn * OUTF + tid] = fmaxf(s, 0.f) + g_relu_sx[bn * OUTF + tid];
    }
}

// ---------------------------------------------------------------------------
extern "C" void kernel_launch(void* const* d_in, const int* in_sizes, int n_in,
                              void* d_out, int out_size, void* d_ws, size_t ws_size,
                              hipStream_t stream) {
    const float* A        = (const float*)d_in[0];
    const float* emb_node = (const float*)d_in[1];
    const float* emb_edge = (const float*)d_in[2];
    const float* W_node   = (const float*)d_in[3];
    const float* b_node   = (const float*)d_in[4];
    const float* W_nodes  = (const float*)d_in[5];
    const float* b_nodes  = (const float*)d_in[6];
    const float* W_edge   = (const float*)d_in[7];
    const float* b_edge   = (const float*)d_in[8];

    float* node_out = (float*)d_out;                 // [8,256,64]
    float* edge_out = node_out + BB * NN * OUTF;     // [8,256,256,64]

    node_proj<<<(BB * NN) / 16, 256, 0, stream>>>(emb_node, W_node, b_node,
                                                  W_nodes, b_nodes, W_edge);
    edge_agg<<<BB * NN, 256, 0, stream>>>(A, emb_edge, b_edge, node_out, edge_out);
}